// Round 9
// baseline (184.108 us; speedup 1.0000x reference)
//
#include <hip/hip_runtime.h>

typedef unsigned short u16;
typedef unsigned int u32;

typedef __bf16 bf16x8 __attribute__((ext_vector_type(8)));
typedef _Float16 f16x8 __attribute__((ext_vector_type(8)));
typedef float f32x4 __attribute__((ext_vector_type(4)));

typedef __attribute__((address_space(1))) u32 as1_u32;
typedef __attribute__((address_space(3))) u32 as3_u32;

#define EKF 0.18033688011112042f  // 0.125 * log2(e), folded into Q at GEMM1

__device__ __forceinline__ u16 f2bf(float x) {
  u32 u = __float_as_uint(x);
  u = u + 0x7fffu + ((u >> 16) & 1u);   // RNE
  return (u16)(u >> 16);
}
__device__ __forceinline__ u32 pack2(float a, float b) {
  return (u32)f2bf(a) | ((u32)f2bf(b) << 16);
}
__device__ __forceinline__ u32 pkf16(float a, float b) {
  return __builtin_bit_cast(u32, __builtin_amdgcn_cvt_pkrtz(a, b));
}
__device__ __forceinline__ u16 f2h(float a) {
  return (u16)(pkf16(a, a) & 0xffffu);
}
__device__ __forceinline__ void gld_lds16(const u16* g, const u16* l) {
  __builtin_amdgcn_global_load_lds((const as1_u32*)g, (as3_u32*)l, 16, 0, 0);
}

// ---------------- fused prepass: x cast + both weight transposes ----------------
__global__ __launch_bounds__(256) void prepass_kernel(const float* __restrict__ x,
                                                      const float* __restrict__ w_qkv,
                                                      const float* __restrict__ w_out,
                                                      u16* __restrict__ xb,
                                                      u16* __restrict__ wqkvT,
                                                      u16* __restrict__ woutT) {
  __shared__ float tile[64][65];
  int bid = blockIdx.x;
  int t = threadIdx.x;
  if (bid < 4096) {
    int i = bid * 256 + t;
    float4 v = ((const float4*)x)[i];
    uint2 r;
    r.x = pack2(v.x, v.y);
    r.y = pack2(v.z, v.w);
    ((uint2*)xb)[i] = r;
    return;
  }
  const float* W;
  u16* WT;
  int K, N, bx, by;
  if (bid < 4096 + 768) {
    int b2 = bid - 4096;
    W = w_qkv; WT = wqkvT; K = 1024; N = 3072; bx = b2 & 15; by = b2 >> 4;
  } else {
    int b2 = bid - 4864;
    W = w_out; WT = woutT; K = 1024; N = 1024; bx = b2 & 15; by = b2 >> 4;
  }
  int k0 = bx * 64, n0 = by * 64;
  int r = t >> 4, c4 = (t & 15) * 4;
#pragma unroll
  for (int i = 0; i < 4; ++i) {
    int row = r + i * 16;
    float4 v = *(const float4*)&W[(size_t)(k0 + row) * N + n0 + c4];
    tile[row][c4 + 0] = v.x; tile[row][c4 + 1] = v.y;
    tile[row][c4 + 2] = v.z; tile[row][c4 + 3] = v.w;
  }
  __syncthreads();
#pragma unroll
  for (int i = 0; i < 4; ++i) {
    int n = r + i * 16;
    uint2 o;
    o.x = pack2(tile[c4 + 0][n], tile[c4 + 1][n]);
    o.y = pack2(tile[c4 + 2][n], tile[c4 + 3][n]);
    *(uint2*)&WT[(size_t)(n0 + n) * K + k0 + c4] = o;
  }
}

// ---------------- bf16 GEMM: computes C^T in regs (swapped MFMA operands) ----------------
// OUT_MODE 0: fp32 C (float4 epilogue).  OUT_MODE 2: qkv-split —
//   q (c<1024): *EKF -> bf16 qk; k (c<2048): bf16 qk; v (c>=2048): f16 direct
//   into vt[bh][d][j] (transposed store; consecutive lanes = consecutive j).
template <int OUT_MODE, int BN>
__global__ __launch_bounds__(256) void gemm_bt_kernel(const u16* __restrict__ A,
                                                      const u16* __restrict__ BT,
                                                      void* __restrict__ Cv,
                                                      u16* __restrict__ VT,
                                                      int M, int N, int K) {
  const int NF = (BN == 128) ? 4 : 2;
  __shared__ __attribute__((aligned(16))) u16 sA[128 * 32];
  __shared__ __attribute__((aligned(16))) u16 sB[BN * 32];
  const int tid = threadIdx.x;
  const int wave = tid >> 6;
  const int lane = tid & 63;
  const int bm = blockIdx.y * 128;
  const int bn = blockIdx.x * BN;
  const int wm = (wave >> 1) * 64;
  const int wn = (wave & 1) * (BN / 2);
  const int lr = lane & 15;
  const int kg = lane >> 4;

  const int srow = tid >> 2;
  const int scol = (tid & 3) * 8;
  const u16* pa0 = A + (size_t)(bm + srow) * K + scol;
  const u16* pa1 = pa0 + (size_t)64 * K;
  const u16* pb0 = BT + (size_t)(bn + srow) * K + scol;
  const u16* pb1 = pb0 + (size_t)64 * K;
  const u16* la = sA + wave * 512;
  const u16* lb = sB + wave * 512;

  f32x4 acc[4][NF];
#pragma unroll
  for (int i = 0; i < 4; i++)
#pragma unroll
    for (int j = 0; j < NF; j++) {
      f32x4 z = {0.f, 0.f, 0.f, 0.f};
      acc[i][j] = z;
    }

  for (int k0 = 0; k0 < K; k0 += 32) {
    __syncthreads();
    gld_lds16(pa0 + k0, la);
    gld_lds16(pa1 + k0, la + 2048);
    gld_lds16(pb0 + k0, lb);
    if (BN == 128) gld_lds16(pb1 + k0, lb + 2048);
    __syncthreads();
    bf16x8 af[4], bfr[NF];
#pragma unroll
    for (int mi = 0; mi < 4; mi++)
      af[mi] = *(const bf16x8*)(sA + (wm + mi * 16 + lr) * 32 + kg * 8);
#pragma unroll
    for (int ni = 0; ni < NF; ni++)
      bfr[ni] = *(const bf16x8*)(sB + (wn + ni * 16 + lr) * 32 + kg * 8);
    // swapped operands: D = (A*B)^T -> lane holds token row lr, 4 consecutive features
#pragma unroll
    for (int mi = 0; mi < 4; mi++)
#pragma unroll
      for (int ni = 0; ni < NF; ni++)
        acc[mi][ni] = __builtin_amdgcn_mfma_f32_16x16x32_bf16(bfr[ni], af[mi], acc[mi][ni], 0, 0, 0);
  }

#pragma unroll
  for (int mi = 0; mi < 4; mi++)
#pragma unroll
    for (int ni = 0; ni < NF; ni++) {
      int r = bm + wm + mi * 16 + lr;        // token (C row)
      int c0 = bn + wn + ni * 16 + kg * 4;   // feature base (4 consecutive)
      f32x4 a = acc[mi][ni];
      if (OUT_MODE == 0) {
        float4 o = make_float4(a[0], a[1], a[2], a[3]);
        *(float4*)&((float*)Cv)[(size_t)r * N + c0] = o;
      } else {
        if (c0 < 1024) {
          uint2 o = make_uint2(pack2(a[0] * EKF, a[1] * EKF), pack2(a[2] * EKF, a[3] * EKF));
          *(uint2*)&((u16*)Cv)[(size_t)r * 2048 + c0] = o;
        } else if (c0 < 2048) {
          uint2 o = make_uint2(pack2(a[0], a[1]), pack2(a[2], a[3]));
          *(uint2*)&((u16*)Cv)[(size_t)r * 2048 + c0] = o;
        } else {
          int cc = c0 - 2048;                 // h = cc>>6, d base = cc&63
          int bh2 = (r >> 11) * 16 + (cc >> 6);
          int j = r & 2047;
          u16* vrow = VT + ((size_t)bh2 * 64 + (cc & 63)) * 2048 + j;
#pragma unroll
          for (int rr = 0; rr < 4; rr++)
            vrow[(size_t)rr * 2048] = f2h(a[rr]);
        }
      }
    }
}

// ---------------- MFMA flash attention v8 (unchanged from R8) ----------------
__global__ __launch_bounds__(256, 4) void attn_mfma_kernel(const u16* __restrict__ qk,
                                                           const u16* __restrict__ vt,
                                                           u16* __restrict__ out) {
  __shared__ __attribute__((aligned(16))) u16 sK[2][64 * 64];  // [j][d] swizzled
  __shared__ __attribute__((aligned(16))) u16 sV[2][64 * 64];  // [d][j] swizzled
  __shared__ __attribute__((aligned(16))) u16 sP[4][16 * 64];  // [q][j] 8B-swizzled

  const int tid = threadIdx.x;
  const int wave = tid >> 6;
  const int lane = tid & 63;
  const int lr = lane & 15;  // q col (B), j/d row (A)
  const int kg = lane >> 4;  // k-group / row-quad
  const int l7 = lr & 7;

  int idx = blockIdx.x;
  int qi = 31 - (idx >> 5);  // heavy q-tiles first
  int bh = idx & 31;
  int b = bh >> 4, h = bh & 15;
  int q0 = qi * 64;

  const u16* qbase = qk + (size_t)b * 2048 * 2048 + h * 64;
  const u16* kbase = qbase + 1024;
  const u16* vbase = vt + (size_t)bh * 64 * 2048;
  u16* obase = out + (size_t)b * 2048 * 1024 + h * 64;

  const int sra = wave * 16 + (lane >> 3);
  const int srb = sra + 8;
  const int sc = lane & 7;
  const u32 koffA = (u32)sra * 2048 + (u32)((sc ^ (sra & 7)) * 8);
  const u32 koffB = (u32)srb * 2048 + (u32)((sc ^ (srb & 7)) * 8);
  const u32 ldsA = (wave * 2 + 0) * 512;  // u16 elements
  const u32 ldsB = (wave * 2 + 1) * 512;

  const int qcol = q0 + wave * 16 + lr;
  bf16x8 qf0, qf1;
  {
    const u16* qrow = qbase + (size_t)qcol * 2048;
    qf0 = *(const bf16x8*)(qrow + kg * 8);
    qf1 = *(const bf16x8*)(qrow + 32 + kg * 8);
  }

  const u32 ka0 = (u32)(lr * 64 + ((kg ^ l7) * 8));
  const u32 ka1 = (u32)(lr * 64 + (((4 + kg) ^ l7) * 8));
  u16* const sPw = sP[wave];
  const u32 pr0 = (u32)(lr * 64 + (((kg * 2) ^ (l7 << 1)) * 4));
  const u32 pr1 = (u32)(lr * 64 + (((8 + kg * 2) ^ (l7 << 1)) * 4));

  f32x4 oacc[4];
#pragma unroll
  for (int i = 0; i < 4; ++i) {
    f32x4 z = {0.f, 0.f, 0.f, 0.f};
    oacc[i] = z;
  }
  float lsum = 0.f;

  const int nrounds = qi + 1;
  gld_lds16(kbase + koffA, sK[0] + ldsA);
  gld_lds16(kbase + koffB, sK[0] + ldsB);
  gld_lds16(vbase + koffA, sV[0] + ldsA);
  gld_lds16(vbase + koffB, sV[0] + ldsB);
  __syncthreads();

  for (int t = 0; t < nrounds; ++t) {
    if (t + 1 < nrounds) {
      int j1 = (t + 1) * 64;
      u16* dK = sK[(t + 1) & 1];
      u16* dV = sV[(t + 1) & 1];
      gld_lds16(kbase + (size_t)j1 * 2048 + koffA, dK + ldsA);
      gld_lds16(kbase + (size_t)j1 * 2048 + koffB, dK + ldsB);
      gld_lds16(vbase + j1 + koffA, dV + ldsA);
      gld_lds16(vbase + j1 + koffB, dV + ldsB);
    }
    const u16* sKb = sK[t & 1];
    const u16* sVb = sV[t & 1];
    const bool diag = (t == qi);

#pragma unroll
    for (int jt = 0; jt < 4; ++jt) {
      u16* pw = sPw + lr * 64 + (((jt * 4 + kg) ^ (l7 << 1)) * 4);
      if (!diag || jt <= wave) {
        bf16x8 kf0 = *(const bf16x8*)(sKb + jt * 1024 + ka0);
        bf16x8 kf1 = *(const bf16x8*)(sKb + jt * 1024 + ka1);
        f32x4 c = {0.f, 0.f, 0.f, 0.f};
        c = __builtin_amdgcn_mfma_f32_16x16x32_bf16(kf0, qf0, c, 0, 0, 0);
        c = __builtin_amdgcn_mfma_f32_16x16x32_bf16(kf1, qf1, c, 0, 0, 0);
        float p0 = exp2f(c[0]);
        float p1 = exp2f(c[1]);
        float p2 = exp2f(c[2]);
        float p3 = exp2f(c[3]);
        if (diag && jt == wave) {
          int jr = kg * 4;
          p0 = (jr + 0 <= lr) ? p0 : 0.f;
          p1 = (jr + 1 <= lr) ? p1 : 0.f;
          p2 = (jr + 2 <= lr) ? p2 : 0.f;
          p3 = (jr + 3 <= lr) ? p3 : 0.f;
        }
        lsum += (p0 + p1) + (p2 + p3);
        *(uint2*)pw = make_uint2(pkf16(p0, p1), pkf16(p2, p3));
      } else {
        *(uint2*)pw = make_uint2(0u, 0u);
      }
    }

    asm volatile("" ::: "memory");  // P writes precede P-frag reads (same wave)

    f16x8 pf0 = *(const f16x8*)(sPw + pr0);
    f16x8 pf1 = *(const f16x8*)(sPw + pr1);
#pragma unroll
    for (int dt = 0; dt < 4; ++dt) {
      f16x8 vf0 = *(const f16x8*)(sVb + dt * 1024 + ka0);
      f16x8 vf1 = *(const f16x8*)(sVb + dt * 1024 + ka1);
      oacc[dt] = __builtin_amdgcn_mfma_f32_16x16x32_f16(vf0, pf0, oacc[dt], 0, 0, 0);
      oacc[dt] = __builtin_amdgcn_mfma_f32_16x16x32_f16(vf1, pf1, oacc[dt], 0, 0, 0);
    }
    __syncthreads();
  }

  lsum += __shfl_xor(lsum, 16);
  lsum += __shfl_xor(lsum, 32);
  float inv = 1.0f / lsum;

  u16* orow = obase + (size_t)qcol * 1024;
#pragma unroll
  for (int dt = 0; dt < 4; ++dt) {
    uint2 o2 = make_uint2(pack2(oacc[dt][0] * inv, oacc[dt][1] * inv),
                          pack2(oacc[dt][2] * inv, oacc[dt][3] * inv));
    *(uint2*)(orow + dt * 16 + kg * 4) = o2;
  }
}

// ---------------- launch ----------------
extern "C" void kernel_launch(void* const* d_in, const int* in_sizes, int n_in,
                              void* d_out, int out_size, void* d_ws, size_t ws_size,
                              hipStream_t stream) {
  const float* x = (const float*)d_in[0];      // [2,2048,1024]
  const float* w_qkv = (const float*)d_in[1];  // [1024,3072]
  const float* w_out = (const float*)d_in[2];  // [1024,1024]
  float* out = (float*)d_out;                  // [2,2048,1024] fp32

  char* ws = (char*)d_ws;
  u16* xb    = (u16*)(ws);                //  8 MB: x bf16 [4096,1024]
  u16* wqkvT = (u16*)(ws + (8u << 20));   //  6 MB: w_qkv^T bf16 [3072,1024]
  u16* woutT = (u16*)(ws + (14u << 20));  //  2 MB: w_out^T bf16 [1024,1024]
  u16* qkb   = (u16*)(ws + (16u << 20));  // 16 MB: q|k bf16 [4096,2048]
  u16* vtb   = (u16*)(ws + (32u << 20));  //  8 MB: V^T f16 [32,64,2048]
  u16* attn  = (u16*)(ws + (40u << 20));  //  8 MB: attn out bf16 [4096,1024]

  prepass_kernel<<<5120, 256, 0, stream>>>(x, w_qkv, w_out, xb, wqkvT, woutT);

  // qkv: q/k -> qkb (coalesced), v -> vtb direct transposed
  gemm_bt_kernel<2, 128><<<dim3(3072 / 128, 4096 / 128), 256, 0, stream>>>(
      xb, wqkvT, (void*)qkb, vtb, 4096, 3072, 1024);

  attn_mfma_kernel<<<1024, 256, 0, stream>>>(qkb, vtb, attn);

  gemm_bt_kernel<0, 64><<<dim3(1024 / 64, 4096 / 128), 256, 0, stream>>>(
      attn, woutT, (void*)out, nullptr, 4096, 1024, 1024);
}

// Round 10
// 175.934 us; speedup vs baseline: 1.0465x; 1.0465x over previous
//
#include <hip/hip_runtime.h>

typedef unsigned short u16;
typedef unsigned int u32;

typedef __bf16 bf16x8 __attribute__((ext_vector_type(8)));
typedef _Float16 f16x8 __attribute__((ext_vector_type(8)));
typedef float f32x4 __attribute__((ext_vector_type(4)));

typedef __attribute__((address_space(1))) u32 as1_u32;
typedef __attribute__((address_space(3))) u32 as3_u32;

#define EKF 0.18033688011112042f  // 0.125 * log2(e), folded into Q at GEMM1

__device__ __forceinline__ u16 f2bf(float x) {
  u32 u = __float_as_uint(x);
  u = u + 0x7fffu + ((u >> 16) & 1u);   // RNE
  return (u16)(u >> 16);
}
__device__ __forceinline__ u32 pack2(float a, float b) {
  return (u32)f2bf(a) | ((u32)f2bf(b) << 16);
}
__device__ __forceinline__ u32 pkf16(float a, float b) {
  return __builtin_bit_cast(u32, __builtin_amdgcn_cvt_pkrtz(a, b));
}
__device__ __forceinline__ u16 f2h(float a) {
  return (u16)(pkf16(a, a) & 0xffffu);
}
__device__ __forceinline__ void gld_lds16(const u16* g, const u16* l) {
  __builtin_amdgcn_global_load_lds((const as1_u32*)g, (as3_u32*)l, 16, 0, 0);
}

// ---------------- fused prepass: x cast + both weight transposes ----------------
__global__ __launch_bounds__(256) void prepass_kernel(const float* __restrict__ x,
                                                      const float* __restrict__ w_qkv,
                                                      const float* __restrict__ w_out,
                                                      u16* __restrict__ xb,
                                                      u16* __restrict__ wqkvT,
                                                      u16* __restrict__ woutT) {
  __shared__ float tile[64][65];
  int bid = blockIdx.x;
  int t = threadIdx.x;
  if (bid < 4096) {
    int i = bid * 256 + t;
    float4 v = ((const float4*)x)[i];
    uint2 r;
    r.x = pack2(v.x, v.y);
    r.y = pack2(v.z, v.w);
    ((uint2*)xb)[i] = r;
    return;
  }
  const float* W;
  u16* WT;
  int K, N, bx, by;
  if (bid < 4096 + 768) {
    int b2 = bid - 4096;
    W = w_qkv; WT = wqkvT; K = 1024; N = 3072; bx = b2 & 15; by = b2 >> 4;
  } else {
    int b2 = bid - 4864;
    W = w_out; WT = woutT; K = 1024; N = 1024; bx = b2 & 15; by = b2 >> 4;
  }
  int k0 = bx * 64, n0 = by * 64;
  int r = t >> 4, c4 = (t & 15) * 4;
#pragma unroll
  for (int i = 0; i < 4; ++i) {
    int row = r + i * 16;
    float4 v = *(const float4*)&W[(size_t)(k0 + row) * N + n0 + c4];
    tile[row][c4 + 0] = v.x; tile[row][c4 + 1] = v.y;
    tile[row][c4 + 2] = v.z; tile[row][c4 + 3] = v.w;
  }
  __syncthreads();
#pragma unroll
  for (int i = 0; i < 4; ++i) {
    int n = r + i * 16;
    uint2 o;
    o.x = pack2(tile[c4 + 0][n], tile[c4 + 1][n]);
    o.y = pack2(tile[c4 + 2][n], tile[c4 + 3][n]);
    *(uint2*)&WT[(size_t)(n0 + n) * K + k0 + c4] = o;
  }
}

// ---------------- bf16 GEMM v10: BK=64, swizzled tiles, staged epilogue ----------------
// C^T in regs (swapped MFMA operands): lane holds token row lr, 4 consecutive features.
// OUT_MODE 0: fp32 C via LDS-staged coalesced float4 writes.
// OUT_MODE 2: qkv-split — q/k blocks (bn<2048): bf16 via LDS-staged coalesced uint4
//   writes (q scaled by EKF); V blocks (bn>=2048): f16 direct into vt[bh][d][j].
template <int OUT_MODE, int BN>
__global__ __launch_bounds__(256) void gemm_bt_kernel(const u16* __restrict__ A,
                                                      const u16* __restrict__ BT,
                                                      void* __restrict__ Cv,
                                                      u16* __restrict__ VT,
                                                      int M, int N, int K) {
  const int NF = (BN == 128) ? 4 : 2;
  __shared__ __attribute__((aligned(16))) u16 sA[128 * 64];
  __shared__ __attribute__((aligned(16))) u16 sB[BN * 64];
  const int tid = threadIdx.x;
  const int wave = tid >> 6;
  const int lane = tid & 63;
  const int bm = blockIdx.y * 128;
  const int bn = blockIdx.x * BN;
  const int wm = (wave >> 1) * 64;
  const int wn = (wave & 1) * (BN / 2);
  const int lr = lane & 15;
  const int kg = lane >> 4;
  const int lr7 = lr & 7;

  // staging: inst i covers rows [i*32, i*32+32); thread t -> row sr, 16B chunk sc.
  // XOR swizzle folded into the GLOBAL source column; LDS dest lane-contiguous.
  const int sr = tid >> 3;
  const int sc = tid & 7;
  const int scg = (sc ^ (sr & 7)) * 8;  // swizzled source col (u16)
  const u16* pa = A + (size_t)(bm + sr) * K + scg;
  const u16* pb = BT + (size_t)(bn + sr) * K + scg;
  const u16* la = sA + wave * 512;
  const u16* lb = sB + wave * 512;

  f32x4 acc[4][NF];
#pragma unroll
  for (int i = 0; i < 4; i++)
#pragma unroll
    for (int j = 0; j < NF; j++) {
      f32x4 z = {0.f, 0.f, 0.f, 0.f};
      acc[i][j] = z;
    }

  for (int k0 = 0; k0 < K; k0 += 64) {
    __syncthreads();
#pragma unroll
    for (int i = 0; i < 4; ++i)
      gld_lds16(pa + (size_t)(i * 32) * K + k0, la + i * 2048);
#pragma unroll
    for (int i = 0; i < NF; ++i)
      gld_lds16(pb + (size_t)(i * 32) * K + k0, lb + i * 2048);
    __syncthreads();
#pragma unroll
    for (int kk = 0; kk < 2; ++kk) {
      bf16x8 af[4], bfr[NF];
      const int ch = ((kk * 4 + kg) ^ lr7) * 8;  // swizzled chunk (row&7 == lr&7)
#pragma unroll
      for (int mi = 0; mi < 4; mi++)
        af[mi] = *(const bf16x8*)(sA + (wm + mi * 16 + lr) * 64 + ch);
#pragma unroll
      for (int ni = 0; ni < NF; ni++)
        bfr[ni] = *(const bf16x8*)(sB + (wn + ni * 16 + lr) * 64 + ch);
      // swapped operands: acc = C^T (lane: token lr, features kg*4..+3)
#pragma unroll
      for (int mi = 0; mi < 4; mi++)
#pragma unroll
        for (int ni = 0; ni < NF; ni++)
          acc[mi][ni] = __builtin_amdgcn_mfma_f32_16x16x32_bf16(bfr[ni], af[mi], acc[mi][ni], 0, 0, 0);
    }
  }

  if (OUT_MODE == 0) {
    // fp32 C: stage [128][32] col-halves through LDS, coalesced float4 writes
    float* buf = (float*)sA;
    float* outp = (float*)Cv;
#pragma unroll
    for (int hc = 0; hc < 2; ++hc) {
      __syncthreads();
      if ((wave & 1) == hc) {
#pragma unroll
        for (int mi = 0; mi < 4; mi++)
#pragma unroll
          for (int ni = 0; ni < NF; ni++) {
            int row = wm + mi * 16 + lr;
            int cp = ((ni * 4 + kg) ^ lr7) * 4;  // swizzled 16B chunk
            *(f32x4*)(buf + row * 32 + cp) = acc[mi][ni];
          }
      }
      __syncthreads();
#pragma unroll
      for (int i = 0; i < 4; ++i) {
        int row = i * 32 + (tid >> 3);
        int lc = tid & 7;
        float4 v = *(const float4*)(buf + row * 32 + ((lc ^ (row & 7)) * 4));
        *(float4*)(outp + (size_t)(bm + row) * N + bn + hc * 32 + lc * 4) = v;
      }
    }
  } else if (bn >= 2048) {
    // V block: direct transposed f16 store into vt[bh][d][j]
#pragma unroll
    for (int mi = 0; mi < 4; mi++)
#pragma unroll
      for (int ni = 0; ni < NF; ni++) {
        int r = bm + wm + mi * 16 + lr;
        int cc = bn + wn + ni * 16 + kg * 4 - 2048;
        int bh2 = (r >> 11) * 16 + (cc >> 6);
        int j = r & 2047;
        u16* vrow = VT + ((size_t)bh2 * 64 + (cc & 63)) * 2048 + j;
        f32x4 a = acc[mi][ni];
#pragma unroll
        for (int rr = 0; rr < 4; rr++)
          vrow[(size_t)rr * 2048] = f2h(a[rr]);
      }
  } else {
    // q or k block: stage bf16 [128][64] col-halves through LDS
    float scale = (bn < 1024) ? EKF : 1.0f;
    u16* buf = sA;
    u16* qkp = (u16*)Cv;
#pragma unroll
    for (int hc = 0; hc < 2; ++hc) {
      __syncthreads();
      if ((wave & 1) == hc) {
#pragma unroll
        for (int mi = 0; mi < 4; mi++)
#pragma unroll
          for (int ni = 0; ni < NF; ni++) {
            int row = wm + mi * 16 + lr;
            int sp = ((ni * 4 + kg) ^ (lr & 6)) * 4;  // swizzled 8B subchunk (even-keyed)
            f32x4 a = acc[mi][ni];
            *(uint2*)(buf + row * 64 + sp) =
                make_uint2(pack2(a[0] * scale, a[1] * scale),
                           pack2(a[2] * scale, a[3] * scale));
          }
      }
      __syncthreads();
#pragma unroll
      for (int i = 0; i < 4; ++i) {
        int row = i * 32 + (tid >> 3);
        int lc = tid & 7;
        uint4 v = *(const uint4*)(buf + row * 64 + (((2 * lc) ^ (row & 6)) * 4));
        *(uint4*)(qkp + (size_t)(bm + row) * 2048 + bn + hc * 64 + lc * 8) = v;
      }
    }
  }
}

// ---------------- MFMA flash attention v8 (unchanged from R8/R9) ----------------
__global__ __launch_bounds__(256, 4) void attn_mfma_kernel(const u16* __restrict__ qk,
                                                           const u16* __restrict__ vt,
                                                           u16* __restrict__ out) {
  __shared__ __attribute__((aligned(16))) u16 sK[2][64 * 64];  // [j][d] swizzled
  __shared__ __attribute__((aligned(16))) u16 sV[2][64 * 64];  // [d][j] swizzled
  __shared__ __attribute__((aligned(16))) u16 sP[4][16 * 64];  // [q][j] 8B-swizzled

  const int tid = threadIdx.x;
  const int wave = tid >> 6;
  const int lane = tid & 63;
  const int lr = lane & 15;  // q col (B), j/d row (A)
  const int kg = lane >> 4;  // k-group / row-quad
  const int l7 = lr & 7;

  int idx = blockIdx.x;
  int qi = 31 - (idx >> 5);  // heavy q-tiles first
  int bh = idx & 31;
  int b = bh >> 4, h = bh & 15;
  int q0 = qi * 64;

  const u16* qbase = qk + (size_t)b * 2048 * 2048 + h * 64;
  const u16* kbase = qbase + 1024;
  const u16* vbase = vt + (size_t)bh * 64 * 2048;
  u16* obase = out + (size_t)b * 2048 * 1024 + h * 64;

  const int sra = wave * 16 + (lane >> 3);
  const int srb = sra + 8;
  const int sc = lane & 7;
  const u32 koffA = (u32)sra * 2048 + (u32)((sc ^ (sra & 7)) * 8);
  const u32 koffB = (u32)srb * 2048 + (u32)((sc ^ (srb & 7)) * 8);
  const u32 ldsA = (wave * 2 + 0) * 512;  // u16 elements
  const u32 ldsB = (wave * 2 + 1) * 512;

  const int qcol = q0 + wave * 16 + lr;
  bf16x8 qf0, qf1;
  {
    const u16* qrow = qbase + (size_t)qcol * 2048;
    qf0 = *(const bf16x8*)(qrow + kg * 8);
    qf1 = *(const bf16x8*)(qrow + 32 + kg * 8);
  }

  const u32 ka0 = (u32)(lr * 64 + ((kg ^ l7) * 8));
  const u32 ka1 = (u32)(lr * 64 + (((4 + kg) ^ l7) * 8));
  u16* const sPw = sP[wave];
  const u32 pr0 = (u32)(lr * 64 + (((kg * 2) ^ (l7 << 1)) * 4));
  const u32 pr1 = (u32)(lr * 64 + (((8 + kg * 2) ^ (l7 << 1)) * 4));

  f32x4 oacc[4];
#pragma unroll
  for (int i = 0; i < 4; ++i) {
    f32x4 z = {0.f, 0.f, 0.f, 0.f};
    oacc[i] = z;
  }
  float lsum = 0.f;

  const int nrounds = qi + 1;
  gld_lds16(kbase + koffA, sK[0] + ldsA);
  gld_lds16(kbase + koffB, sK[0] + ldsB);
  gld_lds16(vbase + koffA, sV[0] + ldsA);
  gld_lds16(vbase + koffB, sV[0] + ldsB);
  __syncthreads();

  for (int t = 0; t < nrounds; ++t) {
    if (t + 1 < nrounds) {
      int j1 = (t + 1) * 64;
      u16* dK = sK[(t + 1) & 1];
      u16* dV = sV[(t + 1) & 1];
      gld_lds16(kbase + (size_t)j1 * 2048 + koffA, dK + ldsA);
      gld_lds16(kbase + (size_t)j1 * 2048 + koffB, dK + ldsB);
      gld_lds16(vbase + j1 + koffA, dV + ldsA);
      gld_lds16(vbase + j1 + koffB, dV + ldsB);
    }
    const u16* sKb = sK[t & 1];
    const u16* sVb = sV[t & 1];
    const bool diag = (t == qi);

#pragma unroll
    for (int jt = 0; jt < 4; ++jt) {
      u16* pw = sPw + lr * 64 + (((jt * 4 + kg) ^ (l7 << 1)) * 4);
      if (!diag || jt <= wave) {
        bf16x8 kf0 = *(const bf16x8*)(sKb + jt * 1024 + ka0);
        bf16x8 kf1 = *(const bf16x8*)(sKb + jt * 1024 + ka1);
        f32x4 c = {0.f, 0.f, 0.f, 0.f};
        c = __builtin_amdgcn_mfma_f32_16x16x32_bf16(kf0, qf0, c, 0, 0, 0);
        c = __builtin_amdgcn_mfma_f32_16x16x32_bf16(kf1, qf1, c, 0, 0, 0);
        float p0 = exp2f(c[0]);
        float p1 = exp2f(c[1]);
        float p2 = exp2f(c[2]);
        float p3 = exp2f(c[3]);
        if (diag && jt == wave) {
          int jr = kg * 4;
          p0 = (jr + 0 <= lr) ? p0 : 0.f;
          p1 = (jr + 1 <= lr) ? p1 : 0.f;
          p2 = (jr + 2 <= lr) ? p2 : 0.f;
          p3 = (jr + 3 <= lr) ? p3 : 0.f;
        }
        lsum += (p0 + p1) + (p2 + p3);
        *(uint2*)pw = make_uint2(pkf16(p0, p1), pkf16(p2, p3));
      } else {
        *(uint2*)pw = make_uint2(0u, 0u);
      }
    }

    asm volatile("" ::: "memory");  // P writes precede P-frag reads (same wave)

    f16x8 pf0 = *(const f16x8*)(sPw + pr0);
    f16x8 pf1 = *(const f16x8*)(sPw + pr1);
#pragma unroll
    for (int dt = 0; dt < 4; ++dt) {
      f16x8 vf0 = *(const f16x8*)(sVb + dt * 1024 + ka0);
      f16x8 vf1 = *(const f16x8*)(sVb + dt * 1024 + ka1);
      oacc[dt] = __builtin_amdgcn_mfma_f32_16x16x32_f16(vf0, pf0, oacc[dt], 0, 0, 0);
      oacc[dt] = __builtin_amdgcn_mfma_f32_16x16x32_f16(vf1, pf1, oacc[dt], 0, 0, 0);
    }
    __syncthreads();
  }

  lsum += __shfl_xor(lsum, 16);
  lsum += __shfl_xor(lsum, 32);
  float inv = 1.0f / lsum;

  u16* orow = obase + (size_t)qcol * 1024;
#pragma unroll
  for (int dt = 0; dt < 4; ++dt) {
    uint2 o2 = make_uint2(pack2(oacc[dt][0] * inv, oacc[dt][1] * inv),
                          pack2(oacc[dt][2] * inv, oacc[dt][3] * inv));
    *(uint2*)(orow + dt * 16 + kg * 4) = o2;
  }
}

// ---------------- launch ----------------
extern "C" void kernel_launch(void* const* d_in, const int* in_sizes, int n_in,
                              void* d_out, int out_size, void* d_ws, size_t ws_size,
                              hipStream_t stream) {
  const float* x = (const float*)d_in[0];      // [2,2048,1024]
  const float* w_qkv = (const float*)d_in[1];  // [1024,3072]
  const float* w_out = (const float*)d_in[2];  // [1024,1024]
  float* out = (float*)d_out;                  // [2,2048,1024] fp32

  char* ws = (char*)d_ws;
  u16* xb    = (u16*)(ws);                //  8 MB: x bf16 [4096,1024]
  u16* wqkvT = (u16*)(ws + (8u << 20));   //  6 MB: w_qkv^T bf16 [3072,1024]
  u16* woutT = (u16*)(ws + (14u << 20));  //  2 MB: w_out^T bf16 [1024,1024]
  u16* qkb   = (u16*)(ws + (16u << 20));  // 16 MB: q|k bf16 [4096,2048]
  u16* vtb   = (u16*)(ws + (32u << 20));  //  8 MB: V^T f16 [32,64,2048]
  u16* attn  = (u16*)(ws + (40u << 20));  //  8 MB: attn out bf16 [4096,1024]

  prepass_kernel<<<5120, 256, 0, stream>>>(x, w_qkv, w_out, xb, wqkvT, woutT);

  // qkv: q/k -> qkb (staged, coalesced), v -> vtb direct transposed
  gemm_bt_kernel<2, 128><<<dim3(3072 / 128, 4096 / 128), 256, 0, stream>>>(
      xb, wqkvT, (void*)qkb, vtb, 4096, 3072, 1024);

  attn_mfma_kernel<<<1024, 256, 0, stream>>>(qkb, vtb, attn);

  gemm_bt_kernel<0, 64><<<dim3(1024 / 64, 4096 / 128), 256, 0, stream>>>(
      attn, woutT, (void*)out, nullptr, 4096, 1024, 1024);
}